// Round 1
// baseline (116.948 us; speedup 1.0000x reference)
//
#include <hip/hip_runtime.h>
#include <math.h>

typedef float2 cplx;

__device__ __forceinline__ cplx cmul(cplx a, cplx b){
  return make_float2(a.x*b.x - a.y*b.y, a.x*b.y + a.y*b.x);
}
__device__ __forceinline__ cplx cadd(cplx a, cplx b){ return make_float2(a.x+b.x, a.y+b.y); }
__device__ __forceinline__ cplx mk(float r, float i){ return make_float2(r, i); }

#define NT 512

// 1-qubit gate on bit p: pairs (i0, i0|1<<p), amp' = M * amp
__device__ __forceinline__ void pass_1q(cplx* S, int nAmps, int p,
    cplx m00, cplx m01, cplx m10, cplx m11, int tid)
{
  int half = nAmps >> 1;
  int pm = (1 << p) - 1;
  for (int j = tid; j < half; j += NT){
    int i0 = ((j & ~pm) << 1) | (j & pm);
    int i1 = i0 | (pm + 1);
    cplx a0 = S[i0], a1 = S[i1];
    cplx r0 = cadd(cmul(m00,a0), cmul(m01,a1));
    cplx r1 = cadd(cmul(m10,a0), cmul(m11,a1));
    S[i0] = r0; S[i1] = r1;
  }
}

// controlled-2x2: pairs differ at bit pt; matrix A if control bit (pc)=0 else B
__device__ __forceinline__ void pass_c2(cplx* S, int nAmps, int pc, int pt,
    cplx a00, cplx a01, cplx a10, cplx a11,
    cplx b00, cplx b01, cplx b10, cplx b11, int tid)
{
  int half = nAmps >> 1;
  int pm = (1 << pt) - 1;
  for (int j = tid; j < half; j += NT){
    int i0 = ((j & ~pm) << 1) | (j & pm);
    int i1 = i0 | (pm + 1);
    bool c = (i0 >> pc) & 1;
    cplx m00 = c ? b00 : a00;
    cplx m01 = c ? b01 : a01;
    cplx m10 = c ? b10 : a10;
    cplx m11 = c ? b11 : a11;
    cplx x0 = S[i0], x1 = S[i1];
    cplx r0 = cadd(cmul(m00,x0), cmul(m01,x1));
    cplx r1 = cadd(cmul(m10,x0), cmul(m11,x1));
    S[i0] = r0; S[i1] = r1;
  }
}

// G2 = (I (x) RX[cx,sx]) * CNOT(c->t) * (RY[c2,s2] (x) I) on (bit pc, bit pt)
__device__ __forceinline__ void pass_g2(cplx* S, int nAmps, int pc, int pt,
    float c2, float s2, float cx, float sx, int tid)
{
  int quarter = nAmps >> 2;
  int lo = pc < pt ? pc : pt;
  int hi = pc < pt ? pt : pc;
  int lm = (1 << lo) - 1, hm = (1 << hi) - 1;
  int ic = 1 << pc, it = 1 << pt;
  for (int j = tid; j < quarter; j += NT){
    int t0   = ((j  & ~lm) << 1) | (j  & lm);
    int base = ((t0 & ~hm) << 1) | (t0 & hm);
    cplx a00 = S[base], a01 = S[base|it], a10 = S[base|ic], a11 = S[base|ic|it];
    // RY(c2,s2) on control wire
    cplx b00 = mk(c2*a00.x - s2*a10.x, c2*a00.y - s2*a10.y);
    cplx b01 = mk(c2*a01.x - s2*a11.x, c2*a01.y - s2*a11.y);
    cplx b10 = mk(s2*a00.x + c2*a10.x, s2*a00.y + c2*a10.y);
    cplx b11 = mk(s2*a01.x + c2*a11.x, s2*a01.y + c2*a11.y);
    // CNOT: swap target amps in c=1 half
    cplx c00 = b00, c01 = b01, c10 = b11, c11 = b10;
    // RX(cx,sx) on target: d0 = cx*c0 - i*sx*c1 ; d1 = -i*sx*c0 + cx*c1
    cplx d00 = mk(cx*c00.x + sx*c01.y, cx*c00.y - sx*c01.x);
    cplx d01 = mk(sx*c00.y + cx*c01.x, -sx*c00.x + cx*c01.y);
    cplx d10 = mk(cx*c10.x + sx*c11.y, cx*c10.y - sx*c11.x);
    cplx d11 = mk(sx*c10.y + cx*c11.x, -sx*c10.x + cx*c11.y);
    S[base] = d00; S[base|it] = d01; S[base|ic] = d10; S[base|ic|it] = d11;
  }
}

// one fused conv iteration: RY0(i); [CNOT(i,i+3);RY1(i+3)]; [RY2(i+1);CNOT(i+1,i+4);RX0(i+4)]; [CNOT(i+3,i+1);RX1(i+1)]
__device__ __forceinline__ void iter_block(cplx* S, int nAmps,
    int bi, int bi1, int bi3, int bi4,
    float hc0, float hs0, float hc1, float hs1, float hc2, float hs2,
    float hcx, float hsx, float hc4, float hs4, int tid)
{
  // RY0 on wire i
  pass_1q(S, nAmps, bi, mk(hc0,0), mk(-hs0,0), mk(hs0,0), mk(hc0,0), tid);
  __syncthreads();
  // G1: control=i, target=i+3; c=0: RY1, c=1: RY1*X (columns swapped)
  pass_c2(S, nAmps, bi, bi3,
      mk(hc1,0), mk(-hs1,0), mk(hs1,0), mk(hc1,0),
      mk(-hs1,0), mk(hc1,0), mk(hc1,0), mk(hs1,0), tid);
  __syncthreads();
  // G2 on (i+1, i+4)
  pass_g2(S, nAmps, bi1, bi4, hc2, hs2, hcx, hsx, tid);
  __syncthreads();
  // G3: control=i+3, target=i+1; c=0: RX1, c=1: RX1*X
  pass_c2(S, nAmps, bi3, bi1,
      mk(hc4,0), mk(0,-hs4), mk(0,-hs4), mk(hc4,0),
      mk(0,-hs4), mk(hc4,0), mk(hc4,0), mk(0,-hs4), tid);
  __syncthreads();
}

__global__ __launch_bounds__(NT) void qsim_kernel(
    const float* __restrict__ x,    // (16,1,28,28)
    const float* __restrict__ kp,   // (2,5)
    float* __restrict__ acc)        // (32,12) pre-zeroed; pair = k*16+b
{
  __shared__ cplx S[4096];     // 32 KB: chunk of full state (idx bits 11..0)
  __shared__ cplx Psi[1024];   // 8 KB:  sub-state over wires 0..9
  __shared__ float vc[16], vs[16];
  __shared__ float Pre[64];    // product over wires 10..15
  __shared__ float red[8*12];

  const int tid   = threadIdx.x;
  const int pair  = blockIdx.x & 31;
  const int chunk = blockIdx.x >> 5;   // idx bits 15..12
  const int b = pair & 15;
  const int k = pair >> 4;

  // AvgPool2d(7,7): 28x28 -> 4x4 angles; v_w = (cos(a/2), sin(a/2))
  if (tid < 16){
    int i = tid >> 2, j = tid & 3;
    const float* xb = x + b*784 + (7*i)*28 + 7*j;
    float s = 0.f;
    #pragma unroll
    for (int u = 0; u < 7; ++u)
      #pragma unroll
      for (int v = 0; v < 7; ++v)
        s += xb[u*28 + v];
    float ang = s * (1.0f/49.0f) * 0.5f;
    vc[tid] = cosf(ang);
    vs[tid] = sinf(ang);
  }
  __syncthreads();

  // Psi0: product state over wires 0..9 (Psi bit 9-w <-> global bit 15-w)
  for (int h = tid; h < 1024; h += NT){
    float p = 1.f;
    #pragma unroll
    for (int w = 0; w < 10; ++w)
      p *= ((h >> (9-w)) & 1) ? vs[w] : vc[w];
    Psi[h] = mk(p, 0.f);
  }
  // P: product over wires 10..15 (global bits 5..0)
  if (tid < 64){
    float p = 1.f;
    #pragma unroll
    for (int w = 10; w < 16; ++w)
      p *= ((tid >> (15-w)) & 1) ? vs[w] : vc[w];
    Pre[tid] = p;
  }

  // shared conv angles (uniform per block)
  const float* p5 = kp + k*5;
  float hc0 = cosf(p5[0]*0.5f), hs0 = sinf(p5[0]*0.5f);
  float hc1 = cosf(p5[1]*0.5f), hs1 = sinf(p5[1]*0.5f);
  float hc2 = cosf(p5[2]*0.5f), hs2 = sinf(p5[2]*0.5f);
  float hcx = cosf(p5[3]*0.5f), hsx = sinf(p5[3]*0.5f);
  float hc4 = cosf(p5[4]*0.5f), hs4 = sinf(p5[4]*0.5f);
  __syncthreads();

  // stage 2: iterations 0..5 on Psi (wire w -> bit 9-w)
  for (int i = 0; i < 6; ++i){
    iter_block(Psi, 1024, 9-i, 8-i, 6-i, 5-i,
               hc0,hs0,hc1,hs1,hc2,hs2,hcx,hsx,hc4,hs4, tid);
  }

  // expand: full-state amp(idx) = Psi[idx>>6] * Pre[idx&63], idx = (chunk<<12)|l
  for (int l = tid; l < 4096; l += NT){
    cplx ph = Psi[(chunk << 6) | (l >> 6)];
    float pr = Pre[l & 63];
    S[l] = mk(ph.x * pr, ph.y * pr);
  }
  __syncthreads();

  // stage 3: iterations 6..11 on chunk (wire w -> bit 15-w, all <= 11)
  for (int i = 6; i < 12; ++i){
    iter_block(S, 4096, 15-i, 14-i, 12-i, 11-i,
               hc0,hs0,hc1,hs1,hc2,hs2,hcx,hsx,hc4,hs4, tid);
  }

  // measurement: final CNOT block folded into parity masks
  // E[Z_w] = sum p(y) * (-1)^popc(y & (0x1B << (11-w)))  (wires {w,w+1,w+3,w+4})
  float a12[12];
  #pragma unroll
  for (int w = 0; w < 12; ++w) a12[w] = 0.f;
  for (int l = tid; l < 4096; l += NT){
    int idx = (chunk << 12) | l;
    cplx v = S[l];
    float p = v.x*v.x + v.y*v.y;
    #pragma unroll
    for (int w = 0; w < 12; ++w){
      int par = __popc(idx & (27 << (11-w))) & 1;
      a12[w] += par ? -p : p;
    }
  }
  #pragma unroll
  for (int off = 32; off > 0; off >>= 1)
    #pragma unroll
    for (int w = 0; w < 12; ++w)
      a12[w] += __shfl_down(a12[w], off, 64);
  int lane = tid & 63, wv = tid >> 6;
  if (lane == 0){
    #pragma unroll
    for (int w = 0; w < 12; ++w) red[wv*12 + w] = a12[w];
  }
  __syncthreads();
  if (tid < 12){
    float s = 0.f;
    #pragma unroll
    for (int q = 0; q < 8; ++q) s += red[q*12 + tid];
    atomicAdd(&acc[pair*12 + tid], s);
  }
}

__global__ __launch_bounds__(256) void mlp_kernel(
    const float* __restrict__ acc,
    const float* __restrict__ w1, const float* __restrict__ b1,
    const float* __restrict__ w2, const float* __restrict__ b2,
    const float* __restrict__ w3, const float* __restrict__ b3,
    float* __restrict__ out)
{
  __shared__ float feats[16*24];
  __shared__ float h1[16*128];
  __shared__ float h2[16*64];
  int tid = threadIdx.x;
  for (int t = tid; t < 384; t += 256){
    int b = t / 24, col = t % 24;
    int k = col / 12, w = col % 12;
    feats[t] = acc[(k*16 + b)*12 + w];
  }
  __syncthreads();
  for (int e = tid; e < 2048; e += 256){
    int b = e >> 7, j = e & 127;
    float s = b1[j];
    #pragma unroll
    for (int q = 0; q < 24; ++q) s = fmaf(feats[b*24 + q], w1[j*24 + q], s);
    h1[e] = fmaxf(s, 0.f);
  }
  __syncthreads();
  for (int e = tid; e < 1024; e += 256){
    int b = e >> 6, j = e & 63;
    float s = b2[j];
    #pragma unroll
    for (int q = 0; q < 128; ++q) s = fmaf(h1[b*128 + q], w2[j*128 + q], s);
    h2[e] = fmaxf(s, 0.f);
  }
  __syncthreads();
  if (tid < 64){
    int b = tid >> 2, j = tid & 3;
    float s = b3[j];
    #pragma unroll
    for (int q = 0; q < 64; ++q) s = fmaf(h2[b*64 + q], w3[j*64 + q], s);
    out[tid] = s;
  }
}

extern "C" void kernel_launch(void* const* d_in, const int* in_sizes, int n_in,
                              void* d_out, int out_size, void* d_ws, size_t ws_size,
                              hipStream_t stream) {
  const float* x  = (const float*)d_in[0];
  const float* kp = (const float*)d_in[1];
  const float* w1 = (const float*)d_in[2];
  const float* b1 = (const float*)d_in[3];
  const float* w2 = (const float*)d_in[4];
  const float* b2 = (const float*)d_in[5];
  const float* w3 = (const float*)d_in[6];
  const float* b3 = (const float*)d_in[7];
  float* out = (float*)d_out;
  float* acc = (float*)d_ws;   // 32*12 floats

  hipMemsetAsync(acc, 0, 32*12*sizeof(float), stream);
  qsim_kernel<<<512, NT, 0, stream>>>(x, kp, acc);
  mlp_kernel<<<1, 256, 0, stream>>>(acc, w1, b1, w2, b2, w3, b3, out);
}